// Round 2
// baseline (447.606 us; speedup 1.0000x reference)
//
#include <hip/hip_runtime.h>
#include <hip/hip_bf16.h>

// Problem constants
constexpr int BB  = 2;
constexpr int CHN = 256;
constexpr int HH  = 80;
constexpr int WW  = 80;
constexpr int EE  = 64;
constexpr int HO  = 160;
constexpr int WO  = 160;

// Workspace layout (float offsets)
constexpr int OFF_WT_EN = 0;                    // [256][64]  w1_en transposed
constexpr int OFF_WT_DE = 16384;                // [256][64]  w1_de transposed
constexpr int OFF_WC    = 32768;                // [64][3][3][25] conv2_k transposed
constexpr int OFF_CES   = 47168;                // [B][4][162][162][16] padded+scrambled ce
constexpr int CES_SZ    = 2 * 4 * 162 * 162 * 16;   // 3,359,232
constexpr int OFF_CDG   = OFF_CES + CES_SZ;     // [B][82][82][64] padded cd
constexpr int CDG_SZ    = 2 * 82 * 82 * 64;     // 860,672
constexpr int OFF_GATE  = OFF_CDG + CDG_SZ;     // [B][80][80]
constexpr int OFF_KERN  = OFF_GATE + 2 * 80 * 80;   // [B][80][80][4][25] softmaxed kernels

// ---------------------------------------------------------------------------
// Prep: transpose weights so inner-loop weight reads are wave-uniform (s_load)
// ---------------------------------------------------------------------------
__global__ __launch_bounds__(256) void fade_prep(
    const float* __restrict__ w1_en, const float* __restrict__ w1_de,
    const float* __restrict__ conv2_k, float* __restrict__ ws) {
  int idx = blockIdx.x * 256 + threadIdx.x;
  if (idx < 16384) {
    int c = idx >> 6, e = idx & 63;           // dest = [c][e]
    ws[OFF_WT_EN + idx] = w1_en[e * CHN + c];
    ws[OFF_WT_DE + idx] = w1_de[e * CHN + c];
  }
  if (idx < 14400) {
    // dest idx = (e*9 + t)*25 + o ; src = conv2_k[(o*64 + e)*9 + t]
    int e = idx / 225, rem = idx % 225, t = rem / 25, o = rem % 25;
    ws[OFF_WC + idx] = conv2_k[(o * EE + e) * 9 + t];
  }
}

// ---------------------------------------------------------------------------
// conv1: part A: ce = 1x1(en) -> scrambled+padded ce_s
//        part B: cd = 1x1(de) -> padded cdg, plus gate = sigmoid(1x1(de))
// ---------------------------------------------------------------------------
__global__ __launch_bounds__(256) void fade_conv1(
    const float* __restrict__ en, const float* __restrict__ de,
    const float* __restrict__ gate_w, const float* __restrict__ gate_b,
    const float* __restrict__ b1_en, float* __restrict__ ws) {
  const float* Wt_en = ws + OFF_WT_EN;
  const float* Wt_de = ws + OFF_WT_DE;
  constexpr int NPA = BB * 162 * 162;   // 52488
  constexpr int NPB = BB * 82 * 82;     // 13448
  int id = blockIdx.x * 256 + threadIdx.x;

  if (id < NPA) {
    int b = id / (162 * 162), r = id % (162 * 162);
    int yy = r / 162, xx = r % 162;
    int y = yy - 1, x = xx - 1;
    float* outp = ws + OFF_CES + ((((size_t)b * 4) * 162 + yy) * 162 + xx) * 16;
    constexpr size_t QSTR = (size_t)162 * 162 * 16;
    if (y >= 0 && y < HO && x >= 0 && x < WO) {
      float acc[64];
#pragma unroll
      for (int e = 0; e < 64; ++e) acc[e] = b1_en[e];
      const float* ep = en + (size_t)b * CHN * HO * WO + (size_t)y * WO + x;
      float cur[8];
#pragma unroll
      for (int j = 0; j < 8; ++j) cur[j] = ep[(size_t)j * HO * WO];
      for (int c0 = 0; c0 < CHN; c0 += 8) {
        float nxt[8];
        if (c0 + 8 < CHN) {
#pragma unroll
          for (int j = 0; j < 8; ++j) nxt[j] = ep[(size_t)(c0 + 8 + j) * HO * WO];
        }
#pragma unroll
        for (int j = 0; j < 8; ++j) {
          float v = cur[j];
          const float* wr = Wt_en + (c0 + j) * 64;
#pragma unroll
          for (int e = 0; e < 64; ++e) acc[e] = fmaf(v, wr[e], acc[e]);
        }
        if (c0 + 8 < CHN) {
#pragma unroll
          for (int j = 0; j < 8; ++j) cur[j] = nxt[j];
        }
      }
      // scrambled write: ce_s[b][q][yy][xx][e'] = acc[4*e' + q]
#pragma unroll
      for (int q = 0; q < 4; ++q) {
        float* op = outp + (size_t)q * QSTR;
#pragma unroll
        for (int e4 = 0; e4 < 4; ++e4) {
          float4 v = make_float4(acc[16 * e4 + q], acc[16 * e4 + 4 + q],
                                 acc[16 * e4 + 8 + q], acc[16 * e4 + 12 + q]);
          *(float4*)(op + e4 * 4) = v;
        }
      }
    } else {
      float4 z = make_float4(0.f, 0.f, 0.f, 0.f);
#pragma unroll
      for (int q = 0; q < 4; ++q)
#pragma unroll
        for (int e4 = 0; e4 < 4; ++e4)
          *(float4*)(outp + (size_t)q * QSTR + e4 * 4) = z;
    }
  } else if (id < NPA + NPB) {
    int id2 = id - NPA;
    int b = id2 / (82 * 82), r = id2 % (82 * 82);
    int yy = r / 82, xx = r % 82;
    int y = yy - 1, x = xx - 1;
    float* cop = ws + OFF_CDG + (((size_t)b * 82 + yy) * 82 + xx) * 64;
    if (y >= 0 && y < HH && x >= 0 && x < WW) {
      float acc[64];
#pragma unroll
      for (int e = 0; e < 64; ++e) acc[e] = 0.f;
      float g = gate_b[0];
      const float* dp = de + (size_t)b * CHN * HH * WW + (size_t)y * WW + x;
      float cur[8];
#pragma unroll
      for (int j = 0; j < 8; ++j) cur[j] = dp[(size_t)j * HH * WW];
      for (int c0 = 0; c0 < CHN; c0 += 8) {
        float nxt[8];
        if (c0 + 8 < CHN) {
#pragma unroll
          for (int j = 0; j < 8; ++j) nxt[j] = dp[(size_t)(c0 + 8 + j) * HH * WW];
        }
#pragma unroll
        for (int j = 0; j < 8; ++j) {
          float v = cur[j];
          const float* wr = Wt_de + (c0 + j) * 64;
#pragma unroll
          for (int e = 0; e < 64; ++e) acc[e] = fmaf(v, wr[e], acc[e]);
          g = fmaf(v, gate_w[c0 + j], g);
        }
        if (c0 + 8 < CHN) {
#pragma unroll
          for (int j = 0; j < 8; ++j) cur[j] = nxt[j];
        }
      }
#pragma unroll
      for (int e4 = 0; e4 < 16; ++e4) {
        float4 v = make_float4(acc[4 * e4], acc[4 * e4 + 1], acc[4 * e4 + 2], acc[4 * e4 + 3]);
        *(float4*)(cop + e4 * 4) = v;
      }
      ws[OFF_GATE + ((size_t)b * 80 + y) * 80 + x] = 1.f / (1.f + __expf(-g));
    } else {
      float4 z = make_float4(0.f, 0.f, 0.f, 0.f);
#pragma unroll
      for (int e4 = 0; e4 < 16; ++e4) *(float4*)(cop + e4 * 4) = z;
    }
  }
}

// ---------------------------------------------------------------------------
// kern: k_en(q) + k_de + 2*bias, softmax over 25 -> KERN[b][h][w][q][o]
// block = 64 cells (8x8) x 4 q = 256 threads
// ---------------------------------------------------------------------------
__global__ __launch_bounds__(256) void fade_kern(
    const float* __restrict__ conv2_b, float* __restrict__ ws) {
  __shared__ float skde[64 * 100];
  const float* WC  = ws + OFF_WC;
  const float* CES = ws + OFF_CES;
  const float* CDG = ws + OFF_CDG;
  int bi = blockIdx.x;
  int b = bi / 100, t = bi % 100;
  int th0 = (t / 10) * 8, tw0 = (t % 10) * 8;
  int tid = threadIdx.x;
  int q = __builtin_amdgcn_readfirstlane(tid >> 6);   // wave-uniform
  int cell = tid & 63;
  int h = th0 + (cell >> 3), w = tw0 + (cell & 7);

  float acc[25];
#pragma unroll
  for (int o = 0; o < 25; ++o) acc[o] = 0.f;

  // phase 1: k_de partial over e in [16q, 16q+16)
#pragma unroll
  for (int di = 0; di < 3; ++di)
#pragma unroll
    for (int dj = 0; dj < 3; ++dj) {
      const float* cp = CDG + (((size_t)b * 82 + (h + di)) * 82 + (w + dj)) * 64 + q * 16;
#pragma unroll
      for (int e4 = 0; e4 < 4; ++e4) {
        float4 v = *(const float4*)(cp + e4 * 4);
        float vals[4] = {v.x, v.y, v.z, v.w};
#pragma unroll
        for (int s = 0; s < 4; ++s) {
          int e = q * 16 + e4 * 4 + s;
          const float* wr = WC + (e * 9 + di * 3 + dj) * 25;
#pragma unroll
          for (int o = 0; o < 25; ++o) acc[o] = fmaf(vals[s], wr[o], acc[o]);
        }
      }
    }

#pragma unroll
  for (int o = 0; o < 25; ++o) skde[cell * 100 + q * 25 + o] = acc[o];
  __syncthreads();
#pragma unroll
  for (int o = 0; o < 25; ++o)
    acc[o] = skde[cell * 100 + o] + skde[cell * 100 + 25 + o] +
             skde[cell * 100 + 50 + o] + skde[cell * 100 + 75 + o] +
             2.f * conv2_b[o];   // bias appears in BOTH k_en and k_de

  // phase 3: k_en for this q. group g uses pads: g0:(t1,l1) g1:(t1,l0) g2:(t0,l1) g3:(t0,l0)
#pragma unroll
  for (int g = 0; g < 4; ++g) {
    const int pt = (g < 2) ? 1 : 0;
    const int pl = (g & 1) ? 0 : 1;
#pragma unroll
    for (int di = 0; di < 3; ++di)
#pragma unroll
      for (int dj = 0; dj < 3; ++dj) {
        int yy = 2 * h + di - pt + 1;
        int xx = 2 * w + dj - pl + 1;
        const float* cp = CES + ((((size_t)b * 4 + q) * 162 + yy) * 162 + xx) * 16;
#pragma unroll
        for (int e4 = 0; e4 < 4; ++e4) {
          float4 v = *(const float4*)(cp + e4 * 4);
          float vals[4] = {v.x, v.y, v.z, v.w};
#pragma unroll
          for (int s = 0; s < 4; ++s) {
            int i = g * 16 + e4 * 4 + s;   // conv input-channel index
            const float* wr = WC + (i * 9 + di * 3 + dj) * 25;
#pragma unroll
            for (int o = 0; o < 25; ++o) acc[o] = fmaf(vals[s], wr[o], acc[o]);
          }
        }
      }
  }

  // softmax over 25
  float m = acc[0];
#pragma unroll
  for (int o = 1; o < 25; ++o) m = fmaxf(m, acc[o]);
  float sum = 0.f;
#pragma unroll
  for (int o = 0; o < 25; ++o) { acc[o] = __expf(acc[o] - m); sum += acc[o]; }
  float inv = 1.f / sum;
  float* kp = ws + OFF_KERN + (((size_t)(b * 6400 + h * 80 + w)) * 4 + q) * 25;
#pragma unroll
  for (int o = 0; o < 25; ++o) kp[o] = acc[o] * inv;
}

// ---------------------------------------------------------------------------
// final: CARAFE + gate blend.  block = 32 cells (8w x 4h) x 8 channel-groups
// ---------------------------------------------------------------------------
__global__ __launch_bounds__(256) void fade_final(
    const float* __restrict__ en, const float* __restrict__ de,
    const float* __restrict__ ws, float* __restrict__ out) {
  __shared__ float sde[8][8 * 13];   // 8 channel planes, 8 rows x 12 cols (stride 13)
  const float* KERN = ws + OFF_KERN;
  const float* GATE = ws + OFF_GATE;
  int bi = blockIdx.x;
  int b = bi / 200, t = bi % 200;
  int th0 = (t / 10) * 4, tw0 = (t % 10) * 8;
  int tid = threadIdx.x;
  int g = tid >> 5, cell = tid & 31;
  int ch = cell >> 3, cw = cell & 7;
  int h = th0 + ch, w = tw0 + cw;

  float kern[100];
  const float* kp = KERN + (size_t)(b * 6400 + h * 80 + w) * 100;
#pragma unroll
  for (int i = 0; i < 25; ++i) {
    float4 v = *(const float4*)(kp + i * 4);
    kern[i * 4 + 0] = v.x; kern[i * 4 + 1] = v.y;
    kern[i * 4 + 2] = v.z; kern[i * 4 + 3] = v.w;
  }
  float gv = GATE[((size_t)b * 80 + h) * 80 + w];
  float gv1 = 1.f - gv;

  for (int cb = 0; cb < 32; ++cb) {
    __syncthreads();
    // stage de tile: 8 channels (one per group), rows th0-2..th0+5, cols tw0-2..tw0+9
    for (int k2 = tid; k2 < 768; k2 += 256) {
      int ci = k2 / 96, rem = k2 % 96, rr = rem / 12, cc2 = rem % 12;
      int c = ci * 32 + cb;
      int dr = th0 - 2 + rr, dc = tw0 - 2 + cc2;
      float v = 0.f;
      if (dr >= 0 && dr < HH && dc >= 0 && dc < WW)
        v = de[((size_t)(b * CHN + c) * HH + dr) * WW + dc];
      sde[ci][rr * 13 + cc2] = v;
    }
    __syncthreads();

    int c = g * 32 + cb;
    float win[25];
#pragma unroll
    for (int di = 0; di < 5; ++di)
#pragma unroll
      for (int dj = 0; dj < 5; ++dj)
        win[di * 5 + dj] = sde[g][(ch + di) * 13 + (cw + dj)];

    const float* ep = en + ((size_t)(b * CHN + c) * HO + 2 * h) * WO + 2 * w;
    float* op = out + ((size_t)(b * CHN + c) * HO + 2 * h) * WO + 2 * w;
#pragma unroll
    for (int s1 = 0; s1 < 2; ++s1) {
      float2 e2 = *(const float2*)(ep + s1 * WO);
      float sum0 = 0.f, sum1 = 0.f;
#pragma unroll
      for (int o = 0; o < 25; ++o) {
        sum0 = fmaf(win[o], kern[(2 * s1 + 0) * 25 + o], sum0);
        sum1 = fmaf(win[o], kern[(2 * s1 + 1) * 25 + o], sum1);
      }
      float2 r;
      r.x = fmaf(gv, e2.x, gv1 * sum0);
      r.y = fmaf(gv, e2.y, gv1 * sum1);
      *(float2*)(op + s1 * WO) = r;
    }
  }
}

// ---------------------------------------------------------------------------
extern "C" void kernel_launch(void* const* d_in, const int* in_sizes, int n_in,
                              void* d_out, int out_size, void* d_ws, size_t ws_size,
                              hipStream_t stream) {
  const float* en      = (const float*)d_in[0];
  const float* de      = (const float*)d_in[1];
  const float* gate_w  = (const float*)d_in[2];
  const float* gate_b  = (const float*)d_in[3];
  const float* w1_en   = (const float*)d_in[4];
  const float* b1_en   = (const float*)d_in[5];
  const float* w1_de   = (const float*)d_in[6];
  const float* conv2_k = (const float*)d_in[7];
  const float* conv2_b = (const float*)d_in[8];
  float* ws  = (float*)d_ws;
  float* out = (float*)d_out;

  hipLaunchKernelGGL(fade_prep,  dim3(64),  dim3(256), 0, stream, w1_en, w1_de, conv2_k, ws);
  hipLaunchKernelGGL(fade_conv1, dim3(258), dim3(256), 0, stream, en, de, gate_w, gate_b, b1_en, ws);
  hipLaunchKernelGGL(fade_kern,  dim3(200), dim3(256), 0, stream, conv2_b, ws);
  hipLaunchKernelGGL(fade_final, dim3(400), dim3(256), 0, stream, en, de, ws, out);
}

// Round 5
// 265.735 us; speedup vs baseline: 1.6844x; 1.6844x over previous
//
#include <hip/hip_runtime.h>
#include <hip/hip_bf16.h>

// Problem constants
constexpr int BB  = 2;
constexpr int CHN = 256;
constexpr int HH  = 80;
constexpr int WW  = 80;
constexpr int EE  = 64;
constexpr int HO  = 160;
constexpr int WO  = 160;

// Workspace layout (float offsets)
constexpr int OFF_WT_EN = 0;                    // [256][64]  w1_en transposed
constexpr int OFF_WT_DE = 16384;                // [256][64]  w1_de transposed
constexpr int OFF_WC    = 32768;                // [64][3][3][25] conv2_k transposed
constexpr int OFF_CES   = 47168;                // [B][4][162][162][16] padded+scrambled ce
constexpr int CES_SZ    = 2 * 4 * 162 * 162 * 16;   // 3,359,232
constexpr int OFF_CDG   = OFF_CES + CES_SZ;     // [B][82][82][64] padded cd
constexpr int CDG_SZ    = 2 * 82 * 82 * 64;     // 860,672
constexpr int OFF_GATE  = OFF_CDG + CDG_SZ;     // [B][80][80]
constexpr int OFF_KERN  = OFF_GATE + 2 * 80 * 80;   // [B][80][80][4][25] softmaxed kernels

constexpr int NPA = BB * 162 * 162;   // 52488
constexpr int NPB = BB * 82 * 82;     // 13448

// ---------------------------------------------------------------------------
// Prep: transpose weights so inner-loop weight reads are wave-uniform (s_load)
// ---------------------------------------------------------------------------
__global__ __launch_bounds__(256) void fade_prep(
    const float* __restrict__ w1_en, const float* __restrict__ w1_de,
    const float* __restrict__ conv2_k, float* __restrict__ ws) {
  int idx = blockIdx.x * 256 + threadIdx.x;
  if (idx < 16384) {
    int c = idx >> 6, e = idx & 63;           // dest = [c][e]
    ws[OFF_WT_EN + idx] = w1_en[e * CHN + c];
    ws[OFF_WT_DE + idx] = w1_de[e * CHN + c];
  }
  if (idx < 14400) {
    // dest idx = (e*9 + t)*25 + o ; src = conv2_k[(o*64 + e)*9 + t]
    int e = idx / 225, rem = idx % 225, t = rem / 25, o = rem % 25;
    ws[OFF_WC + idx] = conv2_k[(o * EE + e) * 9 + t];
  }
}

// ---------------------------------------------------------------------------
// conv1: block = 64 positions x 4 e-groups (one wave each).
//   part A (pos < NPA): ce = 1x1(en) -> scrambled+padded ce_s
//   part B:             cd = 1x1(de) -> padded cdg, + gate
// ---------------------------------------------------------------------------
__global__ __launch_bounds__(256) void fade_conv1(
    const float* __restrict__ en, const float* __restrict__ de,
    const float* __restrict__ gate_w, const float* __restrict__ gate_b,
    const float* __restrict__ b1_en,
    const float* __restrict__ wt_en, const float* __restrict__ wt_de,
    float* __restrict__ ces, float* __restrict__ cdg,
    float* __restrict__ gateo) {
  int tid = threadIdx.x;
  int id64 = tid & 63;
  int eg = __builtin_amdgcn_readfirstlane(tid >> 6);   // 0..3, wave-uniform
  int pos = blockIdx.x * 64 + id64;

  if (pos < NPA) {
    int b = pos / (162 * 162), r = pos % (162 * 162);
    int yy = r / 162, xx = r % 162;
    int y = yy - 1, x = xx - 1;
    float* outp = ces + ((((size_t)b * 4) * 162 + yy) * 162 + xx) * 16;
    constexpr size_t QSTR = (size_t)162 * 162 * 16;
    if (y >= 0 && y < HO && x >= 0 && x < WO) {
      float acc[16];
#pragma unroll
      for (int e = 0; e < 16; ++e) acc[e] = b1_en[eg * 16 + e];
      const float* ep = en + (size_t)b * CHN * HO * WO + (size_t)y * WO + x;
      float cur[8];
#pragma unroll
      for (int j = 0; j < 8; ++j) cur[j] = ep[(size_t)j * HO * WO];
      for (int c0 = 0; c0 < CHN; c0 += 8) {
        float nxt[8];
        if (c0 + 8 < CHN) {
#pragma unroll
          for (int j = 0; j < 8; ++j) nxt[j] = ep[(size_t)(c0 + 8 + j) * HO * WO];
        }
#pragma unroll
        for (int j = 0; j < 8; ++j) {
          float v = cur[j];
          const float* wr = wt_en + (c0 + j) * 64 + eg * 16;
#pragma unroll
          for (int e = 0; e < 16; ++e) acc[e] = fmaf(v, wr[e], acc[e]);
        }
        if (c0 + 8 < CHN) {
#pragma unroll
          for (int j = 0; j < 8; ++j) cur[j] = nxt[j];
        }
      }
      // scrambled write: ce_s[b][q][yy][xx][e'] = acc_full[4e'+q]
      // this thread holds acc_full[16eg .. 16eg+16) -> e' block [4eg, 4eg+4)
#pragma unroll
      for (int q = 0; q < 4; ++q) {
        float4 v = make_float4(acc[q], acc[4 + q], acc[8 + q], acc[12 + q]);
        *(float4*)(outp + (size_t)q * QSTR + eg * 4) = v;
      }
    } else {
      float4 z = make_float4(0.f, 0.f, 0.f, 0.f);
#pragma unroll
      for (int q = 0; q < 4; ++q)
        *(float4*)(outp + (size_t)q * QSTR + eg * 4) = z;
    }
  } else if (pos < NPA + NPB) {
    int pos2 = pos - NPA;
    int b = pos2 / (82 * 82), r = pos2 % (82 * 82);
    int yy = r / 82, xx = r % 82;
    int y = yy - 1, x = xx - 1;
    float* cop = cdg + (((size_t)b * 82 + yy) * 82 + xx) * 64 + eg * 16;
    if (y >= 0 && y < HH && x >= 0 && x < WW) {
      float acc[16];
#pragma unroll
      for (int e = 0; e < 16; ++e) acc[e] = 0.f;
      float g = gate_b[0];
      const float* dp = de + (size_t)b * CHN * HH * WW + (size_t)y * WW + x;
      float cur[8];
#pragma unroll
      for (int j = 0; j < 8; ++j) cur[j] = dp[(size_t)j * HH * WW];
      for (int c0 = 0; c0 < CHN; c0 += 8) {
        float nxt[8];
        if (c0 + 8 < CHN) {
#pragma unroll
          for (int j = 0; j < 8; ++j) nxt[j] = dp[(size_t)(c0 + 8 + j) * HH * WW];
        }
#pragma unroll
        for (int j = 0; j < 8; ++j) {
          float v = cur[j];
          const float* wr = wt_de + (c0 + j) * 64 + eg * 16;
#pragma unroll
          for (int e = 0; e < 16; ++e) acc[e] = fmaf(v, wr[e], acc[e]);
          g = fmaf(v, gate_w[c0 + j], g);
        }
        if (c0 + 8 < CHN) {
#pragma unroll
          for (int j = 0; j < 8; ++j) cur[j] = nxt[j];
        }
      }
#pragma unroll
      for (int m = 0; m < 4; ++m) {
        float4 v = make_float4(acc[4 * m], acc[4 * m + 1], acc[4 * m + 2], acc[4 * m + 3]);
        *(float4*)(cop + m * 4) = v;
      }
      if (eg == 0)
        gateo[((size_t)b * 80 + y) * 80 + x] = 1.f / (1.f + __expf(-g));
    } else {
      float4 z = make_float4(0.f, 0.f, 0.f, 0.f);
#pragma unroll
      for (int m = 0; m < 4; ++m) *(float4*)(cop + m * 4) = z;
    }
  }
}

// ---------------------------------------------------------------------------
// kern: block = 512 threads = 8 waves. Wave wv = K-slice (8 conv channels).
// Lanes = 16 cells (4x4) x 4 q.  Partials reduced via LDS, wave-0 softmax.
// ---------------------------------------------------------------------------
__global__ __launch_bounds__(512) void fade_kern(
    const float* __restrict__ WC, const float* __restrict__ CES,
    const float* __restrict__ CDG, const float* __restrict__ conv2_b,
    float* __restrict__ KERN) {
  __shared__ float part[64 * 201];   // [row][wv*25+o], row stride 201 (conflict-free)
  __shared__ float score[64 * 27];
  int bi = blockIdx.x;
  int b = bi / 400, t = bi % 400;
  int th0 = (t / 20) * 4, tw0 = (t % 20) * 4;
  int tid = threadIdx.x;
  int lane = tid & 63;
  int wv = __builtin_amdgcn_readfirstlane(tid >> 6);   // 0..7 K-slice
  int cell = lane >> 2, q = lane & 3;
  int h = th0 + (cell >> 2), w = tw0 + (cell & 3);

  float acc[25];
#pragma unroll
  for (int o = 0; o < 25; ++o) acc[o] = 0.f;

  // --- k_de slice: channels e in [8wv, 8wv+8) (q-redundant, cheap) ---
#pragma unroll
  for (int di = 0; di < 3; ++di)
#pragma unroll
    for (int dj = 0; dj < 3; ++dj) {
      const float* cp = CDG + (((size_t)b * 82 + (h + di)) * 82 + (w + dj)) * 64 + 8 * wv;
      float4 v0 = *(const float4*)(cp);
      float4 v1 = *(const float4*)(cp + 4);
      float vals[8] = {v0.x, v0.y, v0.z, v0.w, v1.x, v1.y, v1.z, v1.w};
#pragma unroll
      for (int k = 0; k < 8; ++k) {
        const float* wr = WC + ((8 * wv + k) * 9 + di * 3 + dj) * 25;
#pragma unroll
        for (int o = 0; o < 25; ++o) acc[o] = fmaf(vals[k], wr[o], acc[o]);
      }
    }

  // --- k_en slice: channels i in [8wv, 8wv+8); pad-group g = wv>>1 ---
  {
    int g = wv >> 1;
    const int pt = (g < 2) ? 1 : 0;
    const int pl = (g & 1) ? 0 : 1;
    const int eb = 8 * (wv & 1);
#pragma unroll
    for (int di = 0; di < 3; ++di)
#pragma unroll
      for (int dj = 0; dj < 3; ++dj) {
        int yy = 2 * h + di - pt + 1;
        int xx = 2 * w + dj - pl + 1;
        const float* cp = CES + ((((size_t)b * 4 + q) * 162 + yy) * 162 + xx) * 16 + eb;
        float4 v0 = *(const float4*)(cp);
        float4 v1 = *(const float4*)(cp + 4);
        float vals[8] = {v0.x, v0.y, v0.z, v0.w, v1.x, v1.y, v1.z, v1.w};
#pragma unroll
        for (int k = 0; k < 8; ++k) {
          const float* wr = WC + ((8 * wv + k) * 9 + di * 3 + dj) * 25;
#pragma unroll
          for (int o = 0; o < 25; ++o) acc[o] = fmaf(vals[k], wr[o], acc[o]);
        }
      }
  }

#pragma unroll
  for (int o = 0; o < 25; ++o) part[lane * 201 + wv * 25 + o] = acc[o];
  __syncthreads();

  // reduce 8 partials per (row, o); thread (row = tid&63, sub = tid>>6)
  {
    int row = tid & 63, sub = tid >> 6;
    int nO = (sub == 7) ? 4 : 3;
    for (int m = 0; m < nO; ++m) {
      int o = sub * 3 + m;
      float s = 0.f;
#pragma unroll
      for (int w8 = 0; w8 < 8; ++w8) s += part[row * 201 + w8 * 25 + o];
      score[row * 27 + o] = s + 2.f * conv2_b[o];   // bias in BOTH k_en and k_de
    }
  }
  __syncthreads();

  // softmax + write: wave 0, one row per lane
  if (tid < 64) {
    float v[25];
#pragma unroll
    for (int o = 0; o < 25; ++o) v[o] = score[tid * 27 + o];
    float m = v[0];
#pragma unroll
    for (int o = 1; o < 25; ++o) m = fmaxf(m, v[o]);
    float sum = 0.f;
#pragma unroll
    for (int o = 0; o < 25; ++o) { v[o] = __expf(v[o] - m); sum += v[o]; }
    float inv = 1.f / sum;
    int cl = tid >> 2, qq = tid & 3;
    int hh = th0 + (cl >> 2), ww2 = tw0 + (cl & 3);
    float* kp = KERN + (((size_t)(b * 6400 + hh * 80 + ww2)) * 4 + qq) * 25;
#pragma unroll
    for (int o = 0; o < 25; ++o) kp[o] = v[o] * inv;
  }
}

// ---------------------------------------------------------------------------
// final: CARAFE + gate blend. Grid = B x 200 tiles x 8 channel-chunks.
// Block = 256 threads = 32 cells (8w x 4h) x 8 sub-groups of 4 channels.
// ---------------------------------------------------------------------------
__global__ __launch_bounds__(256) void fade_final(
    const float* __restrict__ en, const float* __restrict__ de,
    const float* __restrict__ KERN, const float* __restrict__ GATE,
    float* __restrict__ out) {
  __shared__ float sde[32 * 105];   // 32 channels x (8 rows x 13 cols pad)
  int bi = blockIdx.x;
  int b = bi / 1600, r = bi % 1600;
  int t = r >> 3, cc = r & 7;
  int th0 = (t / 10) * 4, tw0 = (t % 10) * 8;
  int tid = threadIdx.x;
  int sg = tid >> 5, cell = tid & 31;
  int chh = cell >> 3, cw = cell & 7;
  int h = th0 + chh, w = tw0 + cw;

  // stage de: channels cc*32 .. +32, rows th0-2..+5, cols tw0-2..+9
  for (int k2 = tid; k2 < 3072; k2 += 256) {
    int ci = k2 / 96, rem = k2 % 96, rr = rem / 12, c2 = rem % 12;
    int dr = th0 - 2 + rr, dc = tw0 - 2 + c2;
    float v = 0.f;
    if (dr >= 0 && dr < HH && dc >= 0 && dc < WW)
      v = de[((size_t)(b * CHN + cc * 32 + ci) * HH + dr) * WW + dc];
    sde[ci * 105 + rr * 13 + c2] = v;
  }
  __syncthreads();

  float kern[100];
  const float* kp = KERN + (size_t)(b * 6400 + h * 80 + w) * 100;
#pragma unroll
  for (int i = 0; i < 25; ++i) {
    float4 v = *(const float4*)(kp + i * 4);
    kern[i * 4 + 0] = v.x; kern[i * 4 + 1] = v.y;
    kern[i * 4 + 2] = v.z; kern[i * 4 + 3] = v.w;
  }
  float gv = GATE[((size_t)b * 80 + h) * 80 + w];
  float gv1 = 1.f - gv;

#pragma unroll
  for (int j = 0; j < 4; ++j) {
    int c = cc * 32 + sg * 4 + j;
    float win[25];
#pragma unroll
    for (int di = 0; di < 5; ++di)
#pragma unroll
      for (int dj = 0; dj < 5; ++dj)
        win[di * 5 + dj] = sde[(sg * 4 + j) * 105 + (chh + di) * 13 + (cw + dj)];

    const float* ep = en + ((size_t)(b * CHN + c) * HO + 2 * h) * WO + 2 * w;
    float* op = out + ((size_t)(b * CHN + c) * HO + 2 * h) * WO + 2 * w;
#pragma unroll
    for (int s1 = 0; s1 < 2; ++s1) {
      float2 e2 = *(const float2*)(ep + s1 * WO);
      float sum0 = 0.f, sum1 = 0.f;
#pragma unroll
      for (int o = 0; o < 25; ++o) {
        sum0 = fmaf(win[o], kern[(2 * s1 + 0) * 25 + o], sum0);
        sum1 = fmaf(win[o], kern[(2 * s1 + 1) * 25 + o], sum1);
      }
      float2 rr;
      rr.x = fmaf(gv, e2.x, gv1 * sum0);
      rr.y = fmaf(gv, e2.y, gv1 * sum1);
      *(float2*)(op + s1 * WO) = rr;
    }
  }
}

// ---------------------------------------------------------------------------
extern "C" void kernel_launch(void* const* d_in, const int* in_sizes, int n_in,
                              void* d_out, int out_size, void* d_ws, size_t ws_size,
                              hipStream_t stream) {
  const float* en      = (const float*)d_in[0];
  const float* de      = (const float*)d_in[1];
  const float* gate_w  = (const float*)d_in[2];
  const float* gate_b  = (const float*)d_in[3];
  const float* w1_en   = (const float*)d_in[4];
  const float* b1_en   = (const float*)d_in[5];
  const float* w1_de   = (const float*)d_in[6];
  const float* conv2_k = (const float*)d_in[7];
  const float* conv2_b = (const float*)d_in[8];
  float* ws  = (float*)d_ws;
  float* out = (float*)d_out;

  float* wt_en = ws + OFF_WT_EN;
  float* wt_de = ws + OFF_WT_DE;
  float* wc    = ws + OFF_WC;
  float* cesb  = ws + OFF_CES;
  float* cdgb  = ws + OFF_CDG;
  float* gateo = ws + OFF_GATE;
  float* kernb = ws + OFF_KERN;

  hipLaunchKernelGGL(fade_prep,  dim3(64),   dim3(256), 0, stream, w1_en, w1_de, conv2_k, ws);
  hipLaunchKernelGGL(fade_conv1, dim3(1031), dim3(256), 0, stream,
                     en, de, gate_w, gate_b, b1_en, wt_en, wt_de, cesb, cdgb, gateo);
  hipLaunchKernelGGL(fade_kern,  dim3(800),  dim3(512), 0, stream,
                     wc, cesb, cdgb, conv2_b, kernb);
  hipLaunchKernelGGL(fade_final, dim3(3200), dim3(256), 0, stream,
                     en, de, kernb, gateo, out);
}

// Round 6
// 264.492 us; speedup vs baseline: 1.6923x; 1.0047x over previous
//
#include <hip/hip_runtime.h>
#include <hip/hip_bf16.h>

// Problem constants
constexpr int BB  = 2;
constexpr int CHN = 256;
constexpr int HH  = 80;
constexpr int WW  = 80;
constexpr int EE  = 64;
constexpr int HO  = 160;
constexpr int WO  = 160;

// Workspace layout (float offsets)
constexpr int OFF_WT_EN = 0;                    // [256][64]  w1_en transposed
constexpr int OFF_WT_DE = 16384;                // [256][64]  w1_de transposed
constexpr int OFF_WC    = 32768;                // [64][3][3][25] conv2_k transposed
constexpr int OFF_CES   = 47168;                // [B][4][162][162][16] padded+scrambled ce
constexpr int CES_SZ    = 2 * 4 * 162 * 162 * 16;   // 3,359,232
constexpr int OFF_CDG   = OFF_CES + CES_SZ;     // [B][82][82][64] padded cd
constexpr int CDG_SZ    = 2 * 82 * 82 * 64;     // 860,672
constexpr int OFF_GATE  = OFF_CDG + CDG_SZ;     // [B][80][80]
constexpr int OFF_KERN  = OFF_GATE + 2 * 80 * 80;   // [B][80][80][4][25] softmaxed kernels

constexpr int NPA = BB * 162 * 162;   // 52488
constexpr int NPB = BB * 82 * 82;     // 13448

// ---------------------------------------------------------------------------
// Prep: transpose weights so inner-loop weight reads are wave-uniform (s_load)
// ---------------------------------------------------------------------------
__global__ __launch_bounds__(256) void fade_prep(
    const float* __restrict__ w1_en, const float* __restrict__ w1_de,
    const float* __restrict__ conv2_k, float* __restrict__ ws) {
  int idx = blockIdx.x * 256 + threadIdx.x;
  if (idx < 16384) {
    int c = idx >> 6, e = idx & 63;           // dest = [c][e]
    ws[OFF_WT_EN + idx] = w1_en[e * CHN + c];
    ws[OFF_WT_DE + idx] = w1_de[e * CHN + c];
  }
  if (idx < 14400) {
    // dest idx = (e*9 + t)*25 + o ; src = conv2_k[(o*64 + e)*9 + t]
    int e = idx / 225, rem = idx % 225, t = rem / 25, o = rem % 25;
    ws[OFF_WC + idx] = conv2_k[(o * EE + e) * 9 + t];
  }
}

// ---------------------------------------------------------------------------
// conv1: block = 64 positions x 4 e-groups (one wave each).
//   part A (pos < NPA): ce = 1x1(en) -> scrambled+padded ce_s
//   part B:             cd = 1x1(de) -> padded cdg, + gate
// ---------------------------------------------------------------------------
__global__ __launch_bounds__(256) void fade_conv1(
    const float* __restrict__ en, const float* __restrict__ de,
    const float* __restrict__ gate_w, const float* __restrict__ gate_b,
    const float* __restrict__ b1_en,
    const float* __restrict__ wt_en, const float* __restrict__ wt_de,
    float* __restrict__ ces, float* __restrict__ cdg,
    float* __restrict__ gateo) {
  int tid = threadIdx.x;
  int id64 = tid & 63;
  int eg = __builtin_amdgcn_readfirstlane(tid >> 6);   // 0..3, wave-uniform
  int pos = blockIdx.x * 64 + id64;

  if (pos < NPA) {
    int b = pos / (162 * 162), r = pos % (162 * 162);
    int yy = r / 162, xx = r % 162;
    int y = yy - 1, x = xx - 1;
    float* outp = ces + ((((size_t)b * 4) * 162 + yy) * 162 + xx) * 16;
    constexpr size_t QSTR = (size_t)162 * 162 * 16;
    if (y >= 0 && y < HO && x >= 0 && x < WO) {
      float acc[16];
#pragma unroll
      for (int e = 0; e < 16; ++e) acc[e] = b1_en[eg * 16 + e];
      const float* ep = en + (size_t)b * CHN * HO * WO + (size_t)y * WO + x;
      float cur[8];
#pragma unroll
      for (int j = 0; j < 8; ++j) cur[j] = ep[(size_t)j * HO * WO];
      for (int c0 = 0; c0 < CHN; c0 += 8) {
        float nxt[8];
        if (c0 + 8 < CHN) {
#pragma unroll
          for (int j = 0; j < 8; ++j) nxt[j] = ep[(size_t)(c0 + 8 + j) * HO * WO];
        }
#pragma unroll
        for (int j = 0; j < 8; ++j) {
          float v = cur[j];
          const float* wr = wt_en + (c0 + j) * 64 + eg * 16;
#pragma unroll
          for (int e = 0; e < 16; ++e) acc[e] = fmaf(v, wr[e], acc[e]);
        }
        if (c0 + 8 < CHN) {
#pragma unroll
          for (int j = 0; j < 8; ++j) cur[j] = nxt[j];
        }
      }
      // scrambled write: ce_s[b][q][yy][xx][e'] = acc_full[4e'+q]
      // this thread holds acc_full[16eg .. 16eg+16) -> e' block [4eg, 4eg+4)
#pragma unroll
      for (int q = 0; q < 4; ++q) {
        float4 v = make_float4(acc[q], acc[4 + q], acc[8 + q], acc[12 + q]);
        *(float4*)(outp + (size_t)q * QSTR + eg * 4) = v;
      }
    } else {
      float4 z = make_float4(0.f, 0.f, 0.f, 0.f);
#pragma unroll
      for (int q = 0; q < 4; ++q)
        *(float4*)(outp + (size_t)q * QSTR + eg * 4) = z;
    }
  } else if (pos < NPA + NPB) {
    int pos2 = pos - NPA;
    int b = pos2 / (82 * 82), r = pos2 % (82 * 82);
    int yy = r / 82, xx = r % 82;
    int y = yy - 1, x = xx - 1;
    float* cop = cdg + (((size_t)b * 82 + yy) * 82 + xx) * 64 + eg * 16;
    if (y >= 0 && y < HH && x >= 0 && x < WW) {
      float acc[16];
#pragma unroll
      for (int e = 0; e < 16; ++e) acc[e] = 0.f;
      float g = gate_b[0];
      const float* dp = de + (size_t)b * CHN * HH * WW + (size_t)y * WW + x;
      float cur[8];
#pragma unroll
      for (int j = 0; j < 8; ++j) cur[j] = dp[(size_t)j * HH * WW];
      for (int c0 = 0; c0 < CHN; c0 += 8) {
        float nxt[8];
        if (c0 + 8 < CHN) {
#pragma unroll
          for (int j = 0; j < 8; ++j) nxt[j] = dp[(size_t)(c0 + 8 + j) * HH * WW];
        }
#pragma unroll
        for (int j = 0; j < 8; ++j) {
          float v = cur[j];
          const float* wr = wt_de + (c0 + j) * 64 + eg * 16;
#pragma unroll
          for (int e = 0; e < 16; ++e) acc[e] = fmaf(v, wr[e], acc[e]);
          g = fmaf(v, gate_w[c0 + j], g);
        }
        if (c0 + 8 < CHN) {
#pragma unroll
          for (int j = 0; j < 8; ++j) cur[j] = nxt[j];
        }
      }
#pragma unroll
      for (int m = 0; m < 4; ++m) {
        float4 v = make_float4(acc[4 * m], acc[4 * m + 1], acc[4 * m + 2], acc[4 * m + 3]);
        *(float4*)(cop + m * 4) = v;
      }
      if (eg == 0)
        gateo[((size_t)b * 80 + y) * 80 + x] = 1.f / (1.f + __expf(-g));
    } else {
      float4 z = make_float4(0.f, 0.f, 0.f, 0.f);
#pragma unroll
      for (int m = 0; m < 4; ++m) *(float4*)(cop + m * 4) = z;
    }
  }
}

// ---------------------------------------------------------------------------
// kern: block = 512 threads = 8 waves. Wave wv = K-slice (8 conv channels).
// Lanes = 16 cells (4x4) x 4 q.  Partials reduced via LDS, wave-0 softmax.
// __launch_bounds__(512, 4): LDS already caps at 2 blocks/CU (= 4 waves/SIMD),
// so grant the register allocator 128 VGPRs -> acc[25] stays in registers
// (round-5 profile: VGPR=52, acc spilled to scratch, WRITE_SIZE 10x output).
// ---------------------------------------------------------------------------
__global__ __launch_bounds__(512, 4) void fade_kern(
    const float* __restrict__ WC, const float* __restrict__ CES,
    const float* __restrict__ CDG, const float* __restrict__ conv2_b,
    float* __restrict__ KERN) {
  __shared__ float part[64 * 201];   // [row][wv*25+o], row stride 201 (conflict-free)
  __shared__ float score[64 * 27];
  int bi = blockIdx.x;
  int b = bi / 400, t = bi % 400;
  int th0 = (t / 20) * 4, tw0 = (t % 20) * 4;
  int tid = threadIdx.x;
  int lane = tid & 63;
  int wv = __builtin_amdgcn_readfirstlane(tid >> 6);   // 0..7 K-slice
  int cell = lane >> 2, q = lane & 3;
  int h = th0 + (cell >> 2), w = tw0 + (cell & 3);

  float acc[25];
#pragma unroll
  for (int o = 0; o < 25; ++o) acc[o] = 0.f;

  // --- k_de slice: channels e in [8wv, 8wv+8) (q-redundant, cheap) ---
#pragma unroll
  for (int di = 0; di < 3; ++di)
#pragma unroll
    for (int dj = 0; dj < 3; ++dj) {
      const float* cp = CDG + (((size_t)b * 82 + (h + di)) * 82 + (w + dj)) * 64 + 8 * wv;
      float4 v0 = *(const float4*)(cp);
      float4 v1 = *(const float4*)(cp + 4);
      float vals[8] = {v0.x, v0.y, v0.z, v0.w, v1.x, v1.y, v1.z, v1.w};
#pragma unroll
      for (int k = 0; k < 8; ++k) {
        const float* wr = WC + ((8 * wv + k) * 9 + di * 3 + dj) * 25;
#pragma unroll
        for (int o = 0; o < 25; ++o) acc[o] = fmaf(vals[k], wr[o], acc[o]);
      }
    }

  // --- k_en slice: channels i in [8wv, 8wv+8); pad-group g = wv>>1 ---
  {
    int g = wv >> 1;
    const int pt = (g < 2) ? 1 : 0;
    const int pl = (g & 1) ? 0 : 1;
    const int eb = 8 * (wv & 1);
#pragma unroll
    for (int di = 0; di < 3; ++di)
#pragma unroll
      for (int dj = 0; dj < 3; ++dj) {
        int yy = 2 * h + di - pt + 1;
        int xx = 2 * w + dj - pl + 1;
        const float* cp = CES + ((((size_t)b * 4 + q) * 162 + yy) * 162 + xx) * 16 + eb;
        float4 v0 = *(const float4*)(cp);
        float4 v1 = *(const float4*)(cp + 4);
        float vals[8] = {v0.x, v0.y, v0.z, v0.w, v1.x, v1.y, v1.z, v1.w};
#pragma unroll
        for (int k = 0; k < 8; ++k) {
          const float* wr = WC + ((8 * wv + k) * 9 + di * 3 + dj) * 25;
#pragma unroll
          for (int o = 0; o < 25; ++o) acc[o] = fmaf(vals[k], wr[o], acc[o]);
        }
      }
  }

#pragma unroll
  for (int o = 0; o < 25; ++o) part[lane * 201 + wv * 25 + o] = acc[o];
  __syncthreads();

  // reduce 8 partials per (row, o); thread (row = tid&63, sub = tid>>6)
  {
    int row = tid & 63, sub = tid >> 6;
    int nO = (sub == 7) ? 4 : 3;
    for (int m = 0; m < nO; ++m) {
      int o = sub * 3 + m;
      float s = 0.f;
#pragma unroll
      for (int w8 = 0; w8 < 8; ++w8) s += part[row * 201 + w8 * 25 + o];
      score[row * 27 + o] = s + 2.f * conv2_b[o];   // bias in BOTH k_en and k_de
    }
  }
  __syncthreads();

  // softmax + write: wave 0, one row per lane
  if (tid < 64) {
    float v[25];
#pragma unroll
    for (int o = 0; o < 25; ++o) v[o] = score[tid * 27 + o];
    float m = v[0];
#pragma unroll
    for (int o = 1; o < 25; ++o) m = fmaxf(m, v[o]);
    float sum = 0.f;
#pragma unroll
    for (int o = 0; o < 25; ++o) { v[o] = __expf(v[o] - m); sum += v[o]; }
    float inv = 1.f / sum;
    int cl = tid >> 2, qq = tid & 3;
    int hh = th0 + (cl >> 2), ww2 = tw0 + (cl & 3);
    float* kp = KERN + (((size_t)(b * 6400 + hh * 80 + ww2)) * 4 + qq) * 25;
#pragma unroll
    for (int o = 0; o < 25; ++o) kp[o] = v[o] * inv;
  }
}

// ---------------------------------------------------------------------------
// final: CARAFE + gate blend. Grid = B x 200 tiles x 8 channel-chunks.
// Block = 256 threads = 32 cells (8w x 4h) x 8 sub-groups of 4 channels.
// __launch_bounds__(256, 2): kern[100] per thread needs ~150+ VGPRs; cap 256
// so it stays in registers (spill insurance; same disease as fade_kern r5).
// ---------------------------------------------------------------------------
__global__ __launch_bounds__(256, 2) void fade_final(
    const float* __restrict__ en, const float* __restrict__ de,
    const float* __restrict__ KERN, const float* __restrict__ GATE,
    float* __restrict__ out) {
  __shared__ float sde[32 * 105];   // 32 channels x (8 rows x 13 cols pad)
  int bi = blockIdx.x;
  int b = bi / 1600, r = bi % 1600;
  int t = r >> 3, cc = r & 7;
  int th0 = (t / 10) * 4, tw0 = (t % 10) * 8;
  int tid = threadIdx.x;
  int sg = tid >> 5, cell = tid & 31;
  int chh = cell >> 3, cw = cell & 7;
  int h = th0 + chh, w = tw0 + cw;

  // stage de: channels cc*32 .. +32, rows th0-2..+5, cols tw0-2..+9
  for (int k2 = tid; k2 < 3072; k2 += 256) {
    int ci = k2 / 96, rem = k2 % 96, rr = rem / 12, c2 = rem % 12;
    int dr = th0 - 2 + rr, dc = tw0 - 2 + c2;
    float v = 0.f;
    if (dr >= 0 && dr < HH && dc >= 0 && dc < WW)
      v = de[((size_t)(b * CHN + cc * 32 + ci) * HH + dr) * WW + dc];
    sde[ci * 105 + rr * 13 + c2] = v;
  }
  __syncthreads();

  float kern[100];
  const float* kp = KERN + (size_t)(b * 6400 + h * 80 + w) * 100;
#pragma unroll
  for (int i = 0; i < 25; ++i) {
    float4 v = *(const float4*)(kp + i * 4);
    kern[i * 4 + 0] = v.x; kern[i * 4 + 1] = v.y;
    kern[i * 4 + 2] = v.z; kern[i * 4 + 3] = v.w;
  }
  float gv = GATE[((size_t)b * 80 + h) * 80 + w];
  float gv1 = 1.f - gv;

#pragma unroll
  for (int j = 0; j < 4; ++j) {
    int c = cc * 32 + sg * 4 + j;
    float win[25];
#pragma unroll
    for (int di = 0; di < 5; ++di)
#pragma unroll
      for (int dj = 0; dj < 5; ++dj)
        win[di * 5 + dj] = sde[(sg * 4 + j) * 105 + (chh + di) * 13 + (cw + dj)];

    const float* ep = en + ((size_t)(b * CHN + c) * HO + 2 * h) * WO + 2 * w;
    float* op = out + ((size_t)(b * CHN + c) * HO + 2 * h) * WO + 2 * w;
#pragma unroll
    for (int s1 = 0; s1 < 2; ++s1) {
      float2 e2 = *(const float2*)(ep + s1 * WO);
      float sum0 = 0.f, sum1 = 0.f;
#pragma unroll
      for (int o = 0; o < 25; ++o) {
        sum0 = fmaf(win[o], kern[(2 * s1 + 0) * 25 + o], sum0);
        sum1 = fmaf(win[o], kern[(2 * s1 + 1) * 25 + o], sum1);
      }
      float2 rr;
      rr.x = fmaf(gv, e2.x, gv1 * sum0);
      rr.y = fmaf(gv, e2.y, gv1 * sum1);
      *(float2*)(op + s1 * WO) = rr;
    }
  }
}

// ---------------------------------------------------------------------------
extern "C" void kernel_launch(void* const* d_in, const int* in_sizes, int n_in,
                              void* d_out, int out_size, void* d_ws, size_t ws_size,
                              hipStream_t stream) {
  const float* en      = (const float*)d_in[0];
  const float* de      = (const float*)d_in[1];
  const float* gate_w  = (const float*)d_in[2];
  const float* gate_b  = (const float*)d_in[3];
  const float* w1_en   = (const float*)d_in[4];
  const float* b1_en   = (const float*)d_in[5];
  const float* w1_de   = (const float*)d_in[6];
  const float* conv2_k = (const float*)d_in[7];
  const float* conv2_b = (const float*)d_in[8];
  float* ws  = (float*)d_ws;
  float* out = (float*)d_out;

  float* wt_en = ws + OFF_WT_EN;
  float* wt_de = ws + OFF_WT_DE;
  float* wc    = ws + OFF_WC;
  float* cesb  = ws + OFF_CES;
  float* cdgb  = ws + OFF_CDG;
  float* gateo = ws + OFF_GATE;
  float* kernb = ws + OFF_KERN;

  hipLaunchKernelGGL(fade_prep,  dim3(64),   dim3(256), 0, stream, w1_en, w1_de, conv2_k, ws);
  hipLaunchKernelGGL(fade_conv1, dim3(1031), dim3(256), 0, stream,
                     en, de, gate_w, gate_b, b1_en, wt_en, wt_de, cesb, cdgb, gateo);
  hipLaunchKernelGGL(fade_kern,  dim3(800),  dim3(512), 0, stream,
                     wc, cesb, cdgb, conv2_b, kernb);
  hipLaunchKernelGGL(fade_final, dim3(3200), dim3(256), 0, stream,
                     en, de, kernb, gateo, out);
}

// Round 7
// 146.000 us; speedup vs baseline: 3.0658x; 1.8116x over previous
//
#include <hip/hip_runtime.h>
#include <hip/hip_bf16.h>

// Problem constants
constexpr int BB  = 2;
constexpr int CHN = 256;
constexpr int HH  = 80;
constexpr int WW  = 80;
constexpr int EE  = 64;
constexpr int HO  = 160;
constexpr int WO  = 160;

// Workspace layout (float offsets)
constexpr int OFF_WT_EN = 0;                    // [256][64]  w1_en transposed
constexpr int OFF_WT_DE = 16384;                // [256][64]  w1_de transposed
constexpr int OFF_WC    = 32768;                // [64][3][3][25] conv2_k transposed
constexpr int OFF_CES   = 47168;                // [B][4][162][162][16] padded+scrambled ce
constexpr int CES_SZ    = 2 * 4 * 162 * 162 * 16;   // 3,359,232
constexpr int OFF_CDG   = OFF_CES + CES_SZ;     // [B][82][82][64] padded cd
constexpr int CDG_SZ    = 2 * 82 * 82 * 64;     // 860,672
constexpr int OFF_GATE  = OFF_CDG + CDG_SZ;     // [B][80][80]
constexpr int OFF_KERN  = OFF_GATE + 2 * 80 * 80;   // [B][80][80][25][4] softmaxed (o-major, q-minor!)

constexpr int NPA = BB * 162 * 162;   // 52488
constexpr int NPB = BB * 82 * 82;     // 13448

// X-macro: apply F to 0..24 (forces compile-time indices -> registers; rule #20)
#define REP25(F) F(0) F(1) F(2) F(3) F(4) F(5) F(6) F(7) F(8) F(9) F(10) F(11) \
                 F(12) F(13) F(14) F(15) F(16) F(17) F(18) F(19) F(20) F(21) F(22) F(23) F(24)

// ---------------------------------------------------------------------------
// Prep: transpose weights so inner-loop weight reads are wave-uniform (s_load)
// ---------------------------------------------------------------------------
__global__ __launch_bounds__(256) void fade_prep(
    const float* __restrict__ w1_en, const float* __restrict__ w1_de,
    const float* __restrict__ conv2_k, float* __restrict__ ws) {
  int idx = blockIdx.x * 256 + threadIdx.x;
  if (idx < 16384) {
    int c = idx >> 6, e = idx & 63;           // dest = [c][e]
    ws[OFF_WT_EN + idx] = w1_en[e * CHN + c];
    ws[OFF_WT_DE + idx] = w1_de[e * CHN + c];
  }
  if (idx < 14400) {
    // dest idx = (e*9 + t)*25 + o ; src = conv2_k[(o*64 + e)*9 + t]
    int e = idx / 225, rem = idx % 225, t = rem / 25, o = rem % 25;
    ws[OFF_WC + idx] = conv2_k[(o * EE + e) * 9 + t];
  }
}

// ---------------------------------------------------------------------------
// conv1: block = 64 positions x 4 e-groups (one wave each).
// ---------------------------------------------------------------------------
__global__ __launch_bounds__(256) void fade_conv1(
    const float* __restrict__ en, const float* __restrict__ de,
    const float* __restrict__ gate_w, const float* __restrict__ gate_b,
    const float* __restrict__ b1_en,
    const float* __restrict__ wt_en, const float* __restrict__ wt_de,
    float* __restrict__ ces, float* __restrict__ cdg,
    float* __restrict__ gateo) {
  int tid = threadIdx.x;
  int id64 = tid & 63;
  int eg = __builtin_amdgcn_readfirstlane(tid >> 6);   // 0..3, wave-uniform
  int pos = blockIdx.x * 64 + id64;

  if (pos < NPA) {
    int b = pos / (162 * 162), r = pos % (162 * 162);
    int yy = r / 162, xx = r % 162;
    int y = yy - 1, x = xx - 1;
    float* outp = ces + ((((size_t)b * 4) * 162 + yy) * 162 + xx) * 16;
    constexpr size_t QSTR = (size_t)162 * 162 * 16;
    if (y >= 0 && y < HO && x >= 0 && x < WO) {
      float acc[16];
#pragma unroll
      for (int e = 0; e < 16; ++e) acc[e] = b1_en[eg * 16 + e];
      const float* ep = en + (size_t)b * CHN * HO * WO + (size_t)y * WO + x;
      float cur[8];
#pragma unroll
      for (int j = 0; j < 8; ++j) cur[j] = ep[(size_t)j * HO * WO];
      for (int c0 = 0; c0 < CHN; c0 += 8) {
        float nxt[8];
        if (c0 + 8 < CHN) {
#pragma unroll
          for (int j = 0; j < 8; ++j) nxt[j] = ep[(size_t)(c0 + 8 + j) * HO * WO];
        }
#pragma unroll
        for (int j = 0; j < 8; ++j) {
          float v = cur[j];
          const float* wr = wt_en + (c0 + j) * 64 + eg * 16;
#pragma unroll
          for (int e = 0; e < 16; ++e) acc[e] = fmaf(v, wr[e], acc[e]);
        }
        if (c0 + 8 < CHN) {
#pragma unroll
          for (int j = 0; j < 8; ++j) cur[j] = nxt[j];
        }
      }
#pragma unroll
      for (int q = 0; q < 4; ++q) {
        float4 v = make_float4(acc[q], acc[4 + q], acc[8 + q], acc[12 + q]);
        *(float4*)(outp + (size_t)q * QSTR + eg * 4) = v;
      }
    } else {
      float4 z = make_float4(0.f, 0.f, 0.f, 0.f);
#pragma unroll
      for (int q = 0; q < 4; ++q)
        *(float4*)(outp + (size_t)q * QSTR + eg * 4) = z;
    }
  } else if (pos < NPA + NPB) {
    int pos2 = pos - NPA;
    int b = pos2 / (82 * 82), r = pos2 % (82 * 82);
    int yy = r / 82, xx = r % 82;
    int y = yy - 1, x = xx - 1;
    float* cop = cdg + (((size_t)b * 82 + yy) * 82 + xx) * 64 + eg * 16;
    if (y >= 0 && y < HH && x >= 0 && x < WW) {
      float acc[16];
#pragma unroll
      for (int e = 0; e < 16; ++e) acc[e] = 0.f;
      float g = gate_b[0];
      const float* dp = de + (size_t)b * CHN * HH * WW + (size_t)y * WW + x;
      float cur[8];
#pragma unroll
      for (int j = 0; j < 8; ++j) cur[j] = dp[(size_t)j * HH * WW];
      for (int c0 = 0; c0 < CHN; c0 += 8) {
        float nxt[8];
        if (c0 + 8 < CHN) {
#pragma unroll
          for (int j = 0; j < 8; ++j) nxt[j] = dp[(size_t)(c0 + 8 + j) * HH * WW];
        }
#pragma unroll
        for (int j = 0; j < 8; ++j) {
          float v = cur[j];
          const float* wr = wt_de + (c0 + j) * 64 + eg * 16;
#pragma unroll
          for (int e = 0; e < 16; ++e) acc[e] = fmaf(v, wr[e], acc[e]);
          g = fmaf(v, gate_w[c0 + j], g);
        }
        if (c0 + 8 < CHN) {
#pragma unroll
          for (int j = 0; j < 8; ++j) cur[j] = nxt[j];
        }
      }
#pragma unroll
      for (int m = 0; m < 4; ++m) {
        float4 v = make_float4(acc[4 * m], acc[4 * m + 1], acc[4 * m + 2], acc[4 * m + 3]);
        *(float4*)(cop + m * 4) = v;
      }
      if (eg == 0)
        gateo[((size_t)b * 80 + y) * 80 + x] = 1.f / (1.f + __expf(-g));
    } else {
      float4 z = make_float4(0.f, 0.f, 0.f, 0.f);
#pragma unroll
      for (int m = 0; m < 4; ++m) *(float4*)(cop + m * 4) = z;
    }
  }
}

// ---------------------------------------------------------------------------
// kern: block = 512 threads = 8 waves. Wave wv = K-slice (8 conv channels).
// Lanes = 16 cells (4x4) x 4 q.  Accumulators = 25 NAMED scalars (a0..a24):
// round-5/6 profile proved acc[25] never got SROA-promoted (VGPR=52,
// WRITE_SIZE 10x output = scratch). Named scalars cannot go to scratch.
// ---------------------------------------------------------------------------
__global__ __launch_bounds__(512) void fade_kern(
    const float* __restrict__ WC, const float* __restrict__ CES,
    const float* __restrict__ CDG, const float* __restrict__ conv2_b,
    float* __restrict__ KERN) {
  __shared__ float part[64 * 201];   // [row][wv*25+o], row stride 201 (conflict-free)
  __shared__ float score[64 * 27];
  int bi = blockIdx.x;
  int b = bi / 400, t = bi % 400;
  int th0 = (t / 20) * 4, tw0 = (t % 20) * 4;
  int tid = threadIdx.x;
  int lane = tid & 63;
  int wv = __builtin_amdgcn_readfirstlane(tid >> 6);   // 0..7 K-slice
  int cell = lane >> 2, q = lane & 3;
  int h = th0 + (cell >> 2), w = tw0 + (cell & 3);

#define KDECL_(i) float a##i = 0.f;
  REP25(KDECL_)

  // one channel's 25-FMA block; weight base is wave-uniform -> s_load
#define KCH(val, base) { const float vv = (val); const float* wb = (base); \
    REP25(KFMA_) }
#define KFMA_(i) a##i = fmaf(vv, wb[(i)], a##i);

  // --- k_de slice: channels e in [8wv, 8wv+8) ---
  for (int d = 0; d < 9; ++d) {
    int di = d / 3, dj = d - 3 * di;
    const float* cp = CDG + (((size_t)b * 82 + (h + di)) * 82 + (w + dj)) * 64 + 8 * wv;
    float4 v0 = *(const float4*)(cp);
    float4 v1 = *(const float4*)(cp + 4);
    const float* wt = WC + (8 * wv * 9 + d) * 25;   // + k*225 per channel
    KCH(v0.x, wt)        KCH(v0.y, wt + 225)  KCH(v0.z, wt + 450)  KCH(v0.w, wt + 675)
    KCH(v1.x, wt + 900)  KCH(v1.y, wt + 1125) KCH(v1.z, wt + 1350) KCH(v1.w, wt + 1575)
  }

  // --- k_en slice: channels i in [8wv, 8wv+8); pad-group g = wv>>1 ---
  {
    int g = wv >> 1;
    const int pt = (g < 2) ? 1 : 0;
    const int pl = (g & 1) ? 0 : 1;
    const int eb = 8 * (wv & 1);
    for (int d = 0; d < 9; ++d) {
      int di = d / 3, dj = d - 3 * di;
      int yy = 2 * h + di - pt + 1;
      int xx = 2 * w + dj - pl + 1;
      const float* cp = CES + ((((size_t)b * 4 + q) * 162 + yy) * 162 + xx) * 16 + eb;
      float4 v0 = *(const float4*)(cp);
      float4 v1 = *(const float4*)(cp + 4);
      const float* wt = WC + (8 * wv * 9 + d) * 25;
      KCH(v0.x, wt)        KCH(v0.y, wt + 225)  KCH(v0.z, wt + 450)  KCH(v0.w, wt + 675)
      KCH(v1.x, wt + 900)  KCH(v1.y, wt + 1125) KCH(v1.z, wt + 1350) KCH(v1.w, wt + 1575)
    }
  }

  {
    int pbase = lane * 201 + wv * 25;
#define KST_(i) part[pbase + (i)] = a##i;
    REP25(KST_)
  }
  __syncthreads();

  // reduce 8 partials per (row, o); thread (row = tid&63, sub = tid>>6)
  {
    int row = tid & 63, sub = tid >> 6;
    int nO = (sub == 7) ? 4 : 3;
    for (int m = 0; m < nO; ++m) {
      int o = sub * 3 + m;
      float s = 0.f;
#pragma unroll
      for (int w8 = 0; w8 < 8; ++w8) s += part[row * 201 + w8 * 25 + o];
      score[row * 27 + o] = s + 2.f * conv2_b[o];   // bias in BOTH k_en and k_de
    }
  }
  __syncthreads();

  // softmax + write: wave 0, one row per lane. KERN layout: [site][o][q].
  if (tid < 64) {
    int sbase = tid * 27;
#define SLD_(i) float s##i = score[sbase + (i)];
    REP25(SLD_)
    float mx = s0;
#define SMX_(i) mx = fmaxf(mx, s##i);
    REP25(SMX_)
    float sum = 0.f;
#define SEX_(i) s##i = __expf(s##i - mx); sum += s##i;
    REP25(SEX_)
    float inv = 1.f / sum;
    int cl = tid >> 2, qq = tid & 3;
    int hh = th0 + (cl >> 2), ww2 = tw0 + (cl & 3);
    float* kp = KERN + (size_t)(b * 6400 + hh * 80 + ww2) * 100;
#define SWR_(i) kp[(i) * 4 + qq] = s##i * inv;
    REP25(SWR_)
  }
}

// ---------------------------------------------------------------------------
// final: CARAFE + gate blend. Grid = B x 200 tiles x 8 channel-chunks.
// Block = 256 threads = 32 cells (8w x 4h) x 8 sub-groups of 4 channels.
// KERN is [site][o][q] -> 25 named float4 regs (q = .x/.y/.z/.w = (s1 s2)).
// ---------------------------------------------------------------------------
__global__ __launch_bounds__(256) void fade_final(
    const float* __restrict__ en, const float* __restrict__ de,
    const float* __restrict__ KERN, const float* __restrict__ GATE,
    float* __restrict__ out) {
  __shared__ float sde[32 * 105];   // 32 channels x (8 rows x 13 cols pad)
  int bi = blockIdx.x;
  int b = bi / 1600, r = bi % 1600;
  int t = r >> 3, cc = r & 7;
  int th0 = (t / 10) * 4, tw0 = (t % 10) * 8;
  int tid = threadIdx.x;
  int sg = tid >> 5, cell = tid & 31;
  int chh = cell >> 3, cw = cell & 7;
  int h = th0 + chh, w = tw0 + cw;

  // stage de: channels cc*32 .. +32, rows th0-2..+5, cols tw0-2..+9
  for (int kk = tid; kk < 3072; kk += 256) {
    int ci = kk / 96, rem = kk % 96, rr = rem / 12, c2 = rem % 12;
    int dr = th0 - 2 + rr, dc = tw0 - 2 + c2;
    float v = 0.f;
    if (dr >= 0 && dr < HH && dc >= 0 && dc < WW)
      v = de[((size_t)(b * CHN + cc * 32 + ci) * HH + dr) * WW + dc];
    sde[ci * 105 + rr * 13 + c2] = v;
  }
  __syncthreads();

  const float4* kp4 = (const float4*)(KERN + (size_t)(b * 6400 + h * 80 + w) * 100);
#define FKD_(i) float4 k##i = kp4[(i)];
  REP25(FKD_)
  float gv = GATE[((size_t)b * 80 + h) * 80 + w];
  float gv1 = 1.f - gv;

#pragma unroll
  for (int j = 0; j < 4; ++j) {
    int c = cc * 32 + sg * 4 + j;
    int sbase2 = (sg * 4 + j) * 105 + chh * 13 + cw;
#define FWD_(i) float w##i = sde[sbase2 + ((i) / 5) * 13 + ((i) % 5)];
    REP25(FWD_)
    float s00 = 0.f, s01 = 0.f, s10 = 0.f, s11 = 0.f;
#define FCF_(i) s00 = fmaf(w##i, k##i.x, s00); s01 = fmaf(w##i, k##i.y, s01); \
                s10 = fmaf(w##i, k##i.z, s10); s11 = fmaf(w##i, k##i.w, s11);
    REP25(FCF_)

    const float* ep = en + ((size_t)(b * CHN + c) * HO + 2 * h) * WO + 2 * w;
    float* op = out + ((size_t)(b * CHN + c) * HO + 2 * h) * WO + 2 * w;
    float2 e0 = *(const float2*)(ep);
    float2 e1 = *(const float2*)(ep + WO);
    float2 r0, r1;
    r0.x = fmaf(gv, e0.x, gv1 * s00);
    r0.y = fmaf(gv, e0.y, gv1 * s01);
    r1.x = fmaf(gv, e1.x, gv1 * s10);
    r1.y = fmaf(gv, e1.y, gv1 * s11);
    *(float2*)(op) = r0;
    *(float2*)(op + WO) = r1;
  }
}

// ---------------------------------------------------------------------------
extern "C" void kernel_launch(void* const* d_in, const int* in_sizes, int n_in,
                              void* d_out, int out_size, void* d_ws, size_t ws_size,
                              hipStream_t stream) {
  const float* en      = (const float*)d_in[0];
  const float* de      = (const float*)d_in[1];
  const float* gate_w  = (const float*)d_in[2];
  const float* gate_b  = (const float*)d_in[3];
  const float* w1_en   = (const float*)d_in[4];
  const float* b1_en   = (const float*)d_in[5];
  const float* w1_de   = (const float*)d_in[6];
  const float* conv2_k = (const float*)d_in[7];
  const float* conv2_b = (const float*)d_in[8];
  float* ws  = (float*)d_ws;
  float* out = (float*)d_out;

  float* wt_en = ws + OFF_WT_EN;
  float* wt_de = ws + OFF_WT_DE;
  float* wc    = ws + OFF_WC;
  float* cesb  = ws + OFF_CES;
  float* cdgb  = ws + OFF_CDG;
  float* gateo = ws + OFF_GATE;
  float* kernb = ws + OFF_KERN;

  hipLaunchKernelGGL(fade_prep,  dim3(64),   dim3(256), 0, stream, w1_en, w1_de, conv2_k, ws);
  hipLaunchKernelGGL(fade_conv1, dim3(1031), dim3(256), 0, stream,
                     en, de, gate_w, gate_b, b1_en, wt_en, wt_de, cesb, cdgb, gateo);
  hipLaunchKernelGGL(fade_kern,  dim3(800),  dim3(512), 0, stream,
                     wc, cesb, cdgb, conv2_b, kernb);
  hipLaunchKernelGGL(fade_final, dim3(3200), dim3(256), 0, stream,
                     en, de, kernb, gateo, out);
}